// Round 11
// baseline (182.182 us; speedup 1.0000x reference)
//
#include <hip/hip_runtime.h>
#include <cstddef>

#define BATCH 8
#define NN 1024
#define IN_DIM 768
#define OUT_DIM 96
#define HEADS 8
#define M_ROWS 8192
#define NCOLS 1536

typedef __attribute__((ext_vector_type(8))) short short8;
typedef __attribute__((ext_vector_type(4))) float f32x4;
typedef __attribute__((ext_vector_type(4))) unsigned short ushort4v;
typedef _Float16 half8 __attribute__((ext_vector_type(8)));

typedef __attribute__((address_space(1))) void gvoid_t;
typedef __attribute__((address_space(3))) void lvoid_t;

// async global->LDS, 16B per lane; lds dest = wave-uniform base + lane*16
__device__ __forceinline__ void gload_lds16(const void* g, void* l) {
    __builtin_amdgcn_global_load_lds((gvoid_t*)(unsigned long long)g,
                                     (lvoid_t*)(unsigned int)(unsigned long long)l,
                                     16, 0, 0);
}

// pack two f32 -> one dword of two f16 (RTZ hardware op)
__device__ __forceinline__ unsigned int pkrtz(float a, float b) {
    return __builtin_bit_cast(unsigned int, __builtin_amdgcn_cvt_pkrtz(a, b));
}
__device__ __forceinline__ unsigned short f2h(float x) {
    _Float16 h = (_Float16)x;
    return __builtin_bit_cast(unsigned short, h);
}
__device__ __forceinline__ float h2f(unsigned short u) {
    return (float)__builtin_bit_cast(_Float16, u);
}
__device__ __forceinline__ float tanh_fast(float x) {
    return 1.f - 2.f / (__expf(2.f * x) + 1.f);
}
__device__ __forceinline__ f32x4 mfma16(short8 a, short8 b, f32x4 c) {
    return __builtin_amdgcn_mfma_f32_16x16x32_f16(
        __builtin_bit_cast(half8, a), __builtin_bit_cast(half8, b), c, 0, 0, 0);
}

#define WAIT_VM6() asm volatile("s_waitcnt vmcnt(6)" ::: "memory")
#define WAIT_VM0() asm volatile("s_waitcnt vmcnt(0)" ::: "memory")

// ---------- fused prep: xb + pack_w + pack_hw + pack_abits + zero a_src/a_dst ----------
// UNCHANGED from the passing R8 build.
__global__ __launch_bounds__(256) void prep_kernel(
        const float* __restrict__ feat_in, const float* __restrict__ W,
        const float* __restrict__ Hw, const float* __restrict__ adj,
        unsigned short* __restrict__ Xb, unsigned short* __restrict__ BT,
        unsigned int* __restrict__ abits, float* __restrict__ a_zero) {
    int blk = blockIdx.x;
    int t = threadIdx.x;
    if (blk < 3072) {                                 // feat_in f32 -> f16, 8/thread
        int idx = blk * 256 + t;
        const float4* p = (const float4*)(feat_in + (size_t)idx * 8);
        float4 a = p[0], b = p[1];
        union { unsigned int u4[4]; short8 s8; } pk;
        pk.u4[0] = pkrtz(a.x, a.y);
        pk.u4[1] = pkrtz(a.z, a.w);
        pk.u4[2] = pkrtz(b.x, b.y);
        pk.u4[3] = pkrtz(b.z, b.w);
        *(short8*)(Xb + (size_t)idx * 8) = pk.s8;
    } else if (blk < 5376) {                          // W[h][i][o] -> BT[c][i] f16
        int idx = (blk - 3072) * 256 + t;
        int c = idx / IN_DIM, i = idx % IN_DIM;
        int h = c / OUT_DIM, o = c % OUT_DIM;
        BT[(size_t)c * IN_DIM + i] = f2h(W[((size_t)h * IN_DIM + i) * OUT_DIM + o]);
    } else if (blk < 7680) {                          // Hw[c][i] -> BT[768+c][i] f16
        int idx = (blk - 5376) * 256 + t;
        int c = idx / IN_DIM, i = idx % IN_DIM;
        BT[(size_t)(768 + c) * IN_DIM + i] = f2h(Hw[(size_t)c * IN_DIM + i]);
    } else if (blk < 8704) {                          // adj -> 1-bit mask via ballot
        int blkr = blk - 7680;                        // 0..1023
        int wv = t >> 6, ln = t & 63;
        const float* arow = adj + ((size_t)blkr * 8 + wv * 2) * 1024;
        #pragma unroll
        for (int rr = 0; rr < 2; ++rr) {
            unsigned long long mym = 0;
            #pragma unroll
            for (int it = 0; it < 16; ++it) {
                float v = arow[rr * 1024 + it * 64 + ln];
                unsigned long long m = __ballot(v != 0.f);
                if (ln == it) mym = m;
            }
            if (ln < 16) {
                uint2 st;
                st.x = (unsigned int)mym;
                st.y = (unsigned int)(mym >> 32);
                *(uint2*)(abits + ((size_t)blkr * 8 + wv * 2 + rr) * 32 + ln * 2) = st;
            }
        }
    } else {                                          // zero a_src+a_dst (contiguous 1 MB)
        int idx = (blk - 8704) * 256 + t;
        f32x4 z = {0.f, 0.f, 0.f, 0.f};
        *(f32x4*)(a_zero + (size_t)idx * 8) = z;
        *(f32x4*)(a_zero + (size_t)idx * 8 + 4) = z;
    }
}

// ---------- GEMM1: Xb @ BT^T -> h_bt (f16 [bh][o][n]) + gate (f16) + a_src/a_dst partials ----------
// TALL-BLOCK variant: 256x128 block tile, 256 threads / 4 waves, each wave 64x128
// (4 A-frags + 8 B-frags = 12 ds_read_b128 per 32 MFMAs = 0.375 reads/MFMA vs R8's
// 0.625). Binding resource is total LDS bandwidth (B-tile read-amplification);
// per-CU-step traffic drops 168->144 KB with 2x work per block. Sync skeleton is
// VERBATIM R8 (3-step triple-buffer, waitcnt-before-barrier); only the per-wave
// stage width changes: 6 loads/stage -> vmcnt(6). All outputs BIT-IDENTICAL to R8:
// same per-element MFMA chains, same a_src reduction grouping/order/atomics.
// T2 swizzle algebra unchanged (row-within-16 invariants identical).
__global__ __launch_bounds__(256) void gemm1_kernel(
        const unsigned short* __restrict__ Xb, const unsigned short* __restrict__ BT,
        const float* __restrict__ Hb, const float* __restrict__ w_src,
        const float* __restrict__ w_dst,
        unsigned short* __restrict__ h_bt, unsigned short* __restrict__ gate,
        float* __restrict__ a_src, float* __restrict__ a_dst) {
    __shared__ __align__(16) unsigned short As[3][256 * 32];   // 3 x 16KB
    __shared__ __align__(16) unsigned short Bs[3][128 * 32];   // 3 x 8KB
    __shared__ float hbs[128];
    __shared__ float ws_s[128], wd_s[128];
    int m0 = blockIdx.x * 256;
    int c0 = blockIdx.y * 128;
    int t = threadIdx.x;
    int w = t >> 6, lane = t & 63, l15 = t & 15, quad = lane >> 4;
    if (c0 >= 768) {
        if (t < 128) hbs[t] = Hb[c0 - 768 + t];
    } else {
        if (t < 128) {
            int c = c0 + t;
            int hd = c / OUT_DIM, o = c % OUT_DIM;
            ws_s[t] = w_src[hd * OUT_DIM + o];
            wd_s[t] = w_dst[hd * OUT_DIM + o];
        }
    }
    // stage geometry: A tile 16KB = 16 chunks of 1KB (wave w: chunks w*4..w*4+3);
    // B tile 8KB = 8 chunks (wave w: chunks w*2, w*2+1). 6 loads/wave/stage.
    // chunk u covers rows u*16 + (lane>>2); source sub-block inverse-swizzled.
    int qb = (lane & 3) ^ ((lane >> 3) & 3);       // inverse-swizzled 16B sub-block
    int qo = qb * 8;
    const unsigned short* gA0 = Xb + (size_t)(m0 + w * 64 + (lane >> 2)) * IN_DIM + qo;
    const unsigned short* gB0 = BT + (size_t)(c0 + w * 32 + (lane >> 2)) * IN_DIM + qo;
    // read offsets (ushort units): A rows = w*64 + mt*16 + l15, B cols = nt*16 + l15
    int swz = (quad ^ ((l15 >> 1) & 3)) * 8;
    int aoff = (w * 64 + l15) * 32 + swz;          // + mt*512
    int boff = l15 * 32 + swz;                     // + nt*512

    f32x4 acc[4][8] = {};

    auto stage = [&](unsigned short* Ad, unsigned short* Bd, int koff) {
        #pragma unroll
        for (int cc = 0; cc < 4; ++cc)
            gload_lds16(gA0 + (size_t)cc * 16 * IN_DIM + koff, Ad + (w * 4 + cc) * 512);
        #pragma unroll
        for (int cc = 0; cc < 2; ++cc)
            gload_lds16(gB0 + (size_t)cc * 16 * IN_DIM + koff, Bd + (w * 2 + cc) * 512);
    };
    auto compute = [&](const unsigned short* Ab, const unsigned short* Bb) {
        short8 af[4];
        #pragma unroll
        for (int mt = 0; mt < 4; ++mt)
            af[mt] = *(const short8*)(Ab + aoff + mt * 512);
        #pragma unroll
        for (int nt = 0; nt < 8; ++nt) {
            short8 bfr = *(const short8*)(Bb + boff + nt * 512);
            #pragma unroll
            for (int mt = 0; mt < 4; ++mt)
                acc[mt][nt] = mfma16(af[mt], bfr, acc[mt][nt]);
        }
    };

    // prologue: two tiles in flight (6 loads each)
    stage(&As[0][0], &Bs[0][0], 0);
    stage(&As[1][0], &Bs[1][0], 32);
    // main loop: tiles 0..20 in 3-step groups (buffer index compile-time)
    for (int ts = 0; ts < 21; ts += 3) {
        WAIT_VM6(); __builtin_amdgcn_s_barrier();
        stage(&As[2][0], &Bs[2][0], (ts + 2) * 32);
        compute(&As[0][0], &Bs[0][0]);
        WAIT_VM6(); __builtin_amdgcn_s_barrier();
        stage(&As[0][0], &Bs[0][0], (ts + 3) * 32);
        compute(&As[1][0], &Bs[1][0]);
        WAIT_VM6(); __builtin_amdgcn_s_barrier();
        stage(&As[1][0], &Bs[1][0], (ts + 4) * 32);
        compute(&As[2][0], &Bs[2][0]);
    }
    // tail: tiles 21(b0), 22(b1), 23(b2); 23 still needs staging
    WAIT_VM6(); __builtin_amdgcn_s_barrier();
    stage(&As[2][0], &Bs[2][0], 23 * 32);
    compute(&As[0][0], &Bs[0][0]);
    WAIT_VM6(); __builtin_amdgcn_s_barrier();
    compute(&As[1][0], &Bs[1][0]);
    WAIT_VM0(); __builtin_amdgcn_s_barrier();
    compute(&As[2][0], &Bs[2][0]);

    int b = m0 >> 10;
    if (c0 < 768) {
        int split = (c0 / 96 + 1) * 96 - c0;         // cols belonging to lower head
        int headlo = c0 / 96;
        #pragma unroll
        for (int mt = 0; mt < 4; ++mt) {
            int rowbase = m0 + w * 64 + mt * 16 + quad * 4;
            int nbase = rowbase & 1023;
            #pragma unroll
            for (int nt = 0; nt < 8; ++nt) {
                int c = c0 + nt * 16 + l15;
                int hh = c / OUT_DIM, o = c % OUT_DIM;
                union { unsigned int u2[2]; ushort4v u4; } pk;
                pk.u2[0] = pkrtz(acc[mt][nt][0], acc[mt][nt][1]);
                pk.u2[1] = pkrtz(acc[mt][nt][2], acc[mt][nt][3]);
                *(ushort4v*)(h_bt + ((size_t)(b * 8 + hh) * OUT_DIM + o) * NN + nbase) = pk.u4;
            }
            #pragma unroll
            for (int reg = 0; reg < 4; ++reg) {
                float psA = 0.f, pdA = 0.f, psB = 0.f, pdB = 0.f;
                #pragma unroll
                for (int nt = 0; nt < 8; ++nt) {
                    int cl = nt * 16 + l15;
                    float th = tanh_fast(acc[mt][nt][reg]);
                    float s = th * ws_s[cl], d = th * wd_s[cl];
                    if (cl < split) { psA += s; pdA += d; }
                    else            { psB += s; pdB += d; }
                }
                #pragma unroll
                for (int mk = 1; mk <= 8; mk <<= 1) {
                    psA += __shfl_xor(psA, mk); pdA += __shfl_xor(pdA, mk);
                    psB += __shfl_xor(psB, mk); pdB += __shfl_xor(pdB, mk);
                }
                if (l15 == 0) {
                    int n2 = nbase + reg;
                    int ilo = (b * 8 + headlo) * 1024 + n2;
                    atomicAdd(&a_src[ilo], psA * 1.44269504f);
                    atomicAdd(&a_dst[ilo], pdA * 1.44269504f);
                    atomicAdd(&a_src[ilo + 1024], psB * 1.44269504f);
                    atomicAdd(&a_dst[ilo + 1024], pdB * 1.44269504f);
                }
            }
        }
    } else {
        #pragma unroll
        for (int mt = 0; mt < 4; ++mt) {
            int rowbase = m0 + w * 64 + mt * 16 + quad * 4;
            #pragma unroll
            for (int nt = 0; nt < 8; ++nt) {
                int cl = nt * 16 + l15;
                int cg = c0 - 768 + cl;
                #pragma unroll
                for (int reg = 0; reg < 4; ++reg) {
                    float z = acc[mt][nt][reg] + hbs[cl];
                    float g = __builtin_amdgcn_rcpf(1.f + __builtin_amdgcn_exp2f(-1.44269504f * z));
                    gate[(size_t)(rowbase + reg) * 768 + cg] = f2h(g);
                }
            }
        }
    }
}

// ---------- attention + fused epilogue ----------
// FROZEN at the verified R5/R8 structure (double-buffered, __syncthreads-based).
__global__ __launch_bounds__(256) void attn_kernel(
        const unsigned short* __restrict__ h_bt, const unsigned int* __restrict__ abits,
        const float* __restrict__ a_src_g, const float* __restrict__ a_dst_g,
        const unsigned short* __restrict__ gate, const unsigned short* __restrict__ Xb,
        const float* __restrict__ bias, float* __restrict__ out) {
    __shared__ __align__(16) unsigned short hs[2][96 * 64];
    __shared__ __align__(16) float adst[1024];
    __shared__ float bias_s[96];
    int blk = blockIdx.x;
    int bh = (blk & 7) * 8 + ((blk >> 3) & 7);
    int i0 = (blk >> 6) * 128;                   // 8 i-tiles of 128 rows
    int b = bh >> 3, hh = bh & 7;
    int t = threadIdx.x;
    int w = t >> 6, lane = t & 63, l15 = t & 15, quad = lane >> 4;
    *(f32x4*)(adst + t * 4) = *(const f32x4*)(a_dst_g + bh * 1024 + t * 4);
    if (t < 96) bias_s[t] = bias[t];
    int irowA = i0 + w * 16 + l15;
    int irowB = irowA + 64;
    float siA = a_src_g[bh * 1024 + irowA];
    float siB = a_src_g[bh * 1024 + irowB];
    const unsigned short* hhp = h_bt + (size_t)bh * 96 * NN;
    // DMA tile 0 into hs[0] (4 waves, 3 chunks each)
    #pragma unroll
    for (int cc = 0; cc < 3; ++cc) {
        int u0 = (w * 3 + cc) * 64;
        int p = u0 + lane;
        int r = p >> 3, qs = p & 7, qqb = qs ^ (r & 7);
        gload_lds16(hhp + (size_t)r * NN + qqb * 8, (char*)&hs[0][0] + (size_t)u0 * 16);
    }
    const unsigned int* mrowA = abits + ((size_t)b * NN + irowA) * 32;
    const unsigned int* mrowB = abits + ((size_t)b * NN + irowB) * 32;
    uint2 mwA = *(const uint2*)(mrowA);
    uint2 mwB = *(const uint2*)(mrowB);
    f32x4 accA[7] = {}, accB[7] = {};
    short8 ones = {};
    if (l15 == 0) {
        #pragma unroll
        for (int u = 0; u < 8; ++u) ones[u] = (short)0x3C00;   // f16 1.0
    }
    auto build_af = [&](unsigned int byte, float si, const float* dvp) -> short8 {
        float ev[8];
        #pragma unroll
        for (int u = 0; u < 8; ++u) {
            float s = si + dvp[u];
            float l = fmaxf(s, 0.2f * s);
            float e = __builtin_amdgcn_exp2f(l);
            ev[u] = ((byte >> u) & 1u) ? e : 0.f;
        }
        union { unsigned int u4[4]; short8 s8; } pk;
        pk.u4[0] = pkrtz(ev[0], ev[1]);
        pk.u4[1] = pkrtz(ev[2], ev[3]);
        pk.u4[2] = pkrtz(ev[4], ev[5]);
        pk.u4[3] = pkrtz(ev[6], ev[7]);
        return pk.s8;
    };
    __syncthreads();
    for (int j0 = 0; j0 < 1024; j0 += 64) {
        int cur = (j0 >> 6) & 1;
        int jn = j0 + 64;
        // DMA next h tile into the other buffer (drained by the end-of-iter barrier)
        if (jn < 1024) {
            #pragma unroll
            for (int cc = 0; cc < 3; ++cc) {
                int u0 = (w * 3 + cc) * 64;
                int p = u0 + lane;
                int r = p >> 3, qs = p & 7, qqb = qs ^ (r & 7);
                gload_lds16(hhp + (size_t)r * NN + jn + qqb * 8, (char*)&hs[cur ^ 1][0] + (size_t)u0 * 16);
            }
        }
        // build both row-groups' A fragments; dv (a_dst slice) loaded once, shared
        short8 afA[2], afB[2];
        unsigned int mwsA[2] = {mwA.x, mwA.y};
        unsigned int mwsB[2] = {mwB.x, mwB.y};
        #pragma unroll
        for (int ks = 0; ks < 2; ++ks) {
            f32x4 d0 = *(const f32x4*)(&adst[j0 + ks * 32 + quad * 8]);
            f32x4 d1 = *(const f32x4*)(&adst[j0 + ks * 32 + quad * 8 + 4]);
            float dv[8] = {d0[0], d0[1], d0[2], d0[3], d1[0], d1[1], d1[2], d1[3]};
            unsigned int byA = (mwsA[ks] >> (quad * 8)) & 0xFFu;
            unsigned int byB = (mwsB[ks] >> (quad * 8)) & 0xFFu;
            afA[ks] = build_af(byA, siA, dv);
            afB[ks] = build_af(byB, siB, dv);
        }
        // prefetch masks for next iter
        if (jn < 1024) {
            mwA = *(const uint2*)(mrowA + (jn >> 5));
            mwB = *(const uint2*)(mrowB + (jn >> 5));
        }
        // MFMA on current buffer: each B fragment read once, used by both groups
        #pragma unroll
        for (int ks = 0; ks < 2; ++ks) {
            #pragma unroll
            for (int nt = 0; nt < 6; ++nt) {
                int r = nt * 16 + l15;
                int qs = (ks * 4 + quad) ^ (r & 7);
                short8 bfr = *(const short8*)(&hs[cur][(size_t)(r * 8 + qs) * 8]);
                accA[nt] = mfma16(afA[ks], bfr, accA[nt]);
                accB[nt] = mfma16(afB[ks], bfr, accB[nt]);
            }
            accA[6] = mfma16(afA[ks], ones, accA[6]);
            accB[6] = mfma16(afB[ks], ones, accB[6]);
        }
        __syncthreads();
    }
    // fused epilogue: bias + elu + precomputed f16 gate + f16 x + blend -> out
    auto epilog = [&](const f32x4 (&ac)[7], int rowoff) {
        int rowq = i0 + rowoff + w * 16 + quad * 4;
        #pragma unroll
        for (int reg = 0; reg < 4; ++reg) {
            float ssum = __shfl(ac[6][reg], (lane & 48));   // ones-column holds row sum
            float inv = (ssum > 0.f) ? __builtin_amdgcn_rcpf(ssum) : 0.f;
            int n = rowq + reg;
            size_t mrow_o = ((size_t)b * NN + n) * 768 + hh * 96;
            #pragma unroll
            for (int nt = 0; nt < 6; ++nt) {
                int cl = nt * 16 + l15;
                float v = ac[nt][reg] * inv + bias_s[cl];
                float e = (v > 0.f) ? v : (__builtin_amdgcn_exp2f(v * 1.44269504f) - 1.f);
                float g = h2f(gate[mrow_o + cl]);
                float x = h2f(Xb[mrow_o + cl]);
                out[mrow_o + cl] = x + g * (e - x);
            }
        }
    };
    epilog(accA, 0);
    epilog(accB, 64);
}

extern "C" void kernel_launch(void* const* d_in, const int* in_sizes, int n_in,
                              void* d_out, int out_size, void* d_ws, size_t ws_size,
                              hipStream_t stream) {
    const float* feat_in = (const float*)d_in[0];
    const float* adj     = (const float*)d_in[1];
    const float* W       = (const float*)d_in[2];
    const float* bbias   = (const float*)d_in[3];
    const float* w_src   = (const float*)d_in[4];
    const float* w_dst   = (const float*)d_in[5];
    const float* Hw      = (const float*)d_in[6];
    const float* Hb      = (const float*)d_in[7];
    float* out = (float*)d_out;
    char* base = (char*)d_ws;

    unsigned short* Xb    = (unsigned short*)(base);                 // 12,582,912 B (f16)
    unsigned short* BcatT = (unsigned short*)(base + 12582912);      //  2,359,296 B (f16)
    unsigned short* h_bt  = (unsigned short*)(base + 14942208);      // 12,582,912 B (f16)
    unsigned short* gate  = (unsigned short*)(base + 27525120);      // 12,582,912 B (f16)
    float* a_src = (float*)(base + 40108032);                        //    262,144 B
    float* a_dst = (float*)(base + 40370176);                        //    262,144 B (contiguous after a_src)
    unsigned int* abits = (unsigned int*)(base + 40632320);          //  1,048,576 B (end ~41.7 MB)

    prep_kernel<<<8768, 256, 0, stream>>>(feat_in, W, Hw, adj, Xb, BcatT, abits, a_src);
    gemm1_kernel<<<dim3(M_ROWS / 256, NCOLS / 128), 256, 0, stream>>>(
        Xb, BcatT, Hb, w_src, w_dst, h_bt, gate, a_src, a_dst);
    attn_kernel<<<512, 256, 0, stream>>>(h_bt, abits, a_src, a_dst, gate, Xb, bbias, out);
}

// Round 13
// 175.915 us; speedup vs baseline: 1.0356x; 1.0356x over previous
//
#include <hip/hip_runtime.h>
#include <cstddef>

#define BATCH 8
#define NN 1024
#define IN_DIM 768
#define OUT_DIM 96
#define HEADS 8
#define M_ROWS 8192
#define NCOLS 1536

typedef __attribute__((ext_vector_type(8))) short short8;
typedef __attribute__((ext_vector_type(4))) float f32x4;
typedef __attribute__((ext_vector_type(4))) unsigned short ushort4v;
typedef _Float16 half8 __attribute__((ext_vector_type(8)));

typedef __attribute__((address_space(1))) void gvoid_t;
typedef __attribute__((address_space(3))) void lvoid_t;

// async global->LDS, 16B per lane; lds dest = wave-uniform base + lane*16
__device__ __forceinline__ void gload_lds16(const void* g, void* l) {
    __builtin_amdgcn_global_load_lds((gvoid_t*)(unsigned long long)g,
                                     (lvoid_t*)(unsigned int)(unsigned long long)l,
                                     16, 0, 0);
}

// pack two f32 -> one dword of two f16 (RTZ hardware op)
__device__ __forceinline__ unsigned int pkrtz(float a, float b) {
    return __builtin_bit_cast(unsigned int, __builtin_amdgcn_cvt_pkrtz(a, b));
}
__device__ __forceinline__ unsigned short f2h(float x) {
    _Float16 h = (_Float16)x;
    return __builtin_bit_cast(unsigned short, h);
}
__device__ __forceinline__ float h2f(unsigned short u) {
    return (float)__builtin_bit_cast(_Float16, u);
}
__device__ __forceinline__ float tanh_fast(float x) {
    return 1.f - 2.f / (__expf(2.f * x) + 1.f);
}
__device__ __forceinline__ f32x4 mfma16(short8 a, short8 b, f32x4 c) {
    return __builtin_amdgcn_mfma_f32_16x16x32_f16(
        __builtin_bit_cast(half8, a), __builtin_bit_cast(half8, b), c, 0, 0, 0);
}

#define WAIT_VM4() asm volatile("s_waitcnt vmcnt(4)" ::: "memory")
#define WAIT_VM0() asm volatile("s_waitcnt vmcnt(0)" ::: "memory")

// ---------- fused prep: xb + pack_w + pack_hw + pack_abits + zero a_src/a_dst ----------
// Sections: [0,3072) Xb  [3072,5376) W  [5376,7680) Hw  [7680,8704) abits  [8704,8768) zeros
__global__ __launch_bounds__(256) void prep_kernel(
        const float* __restrict__ feat_in, const float* __restrict__ W,
        const float* __restrict__ Hw, const float* __restrict__ adj,
        unsigned short* __restrict__ Xb, unsigned short* __restrict__ BT,
        unsigned int* __restrict__ abits, float* __restrict__ a_zero) {
    int blk = blockIdx.x;
    int t = threadIdx.x;
    if (blk < 3072) {                                 // feat_in f32 -> f16, 8/thread
        int idx = blk * 256 + t;
        const float4* p = (const float4*)(feat_in + (size_t)idx * 8);
        float4 a = p[0], b = p[1];
        union { unsigned int u4[4]; short8 s8; } pk;
        pk.u4[0] = pkrtz(a.x, a.y);
        pk.u4[1] = pkrtz(a.z, a.w);
        pk.u4[2] = pkrtz(b.x, b.y);
        pk.u4[3] = pkrtz(b.z, b.w);
        *(short8*)(Xb + (size_t)idx * 8) = pk.s8;
    } else if (blk < 5376) {                          // W[h][i][o] -> BT[c][i] f16
        int idx = (blk - 3072) * 256 + t;
        int c = idx / IN_DIM, i = idx % IN_DIM;
        int h = c / OUT_DIM, o = c % OUT_DIM;
        BT[(size_t)c * IN_DIM + i] = f2h(W[((size_t)h * IN_DIM + i) * OUT_DIM + o]);
    } else if (blk < 7680) {                          // Hw[c][i] -> BT[768+c][i] f16
        int idx = (blk - 5376) * 256 + t;
        int c = idx / IN_DIM, i = idx % IN_DIM;
        BT[(size_t)(768 + c) * IN_DIM + i] = f2h(Hw[(size_t)c * IN_DIM + i]);
    } else if (blk < 8704) {                          // adj -> 1-bit mask via ballot
        int blkr = blk - 7680;                        // 0..1023
        int wv = t >> 6, ln = t & 63;
        const float* arow = adj + ((size_t)blkr * 8 + wv * 2) * 1024;
        #pragma unroll
        for (int rr = 0; rr < 2; ++rr) {
            unsigned long long mym = 0;
            #pragma unroll
            for (int it = 0; it < 16; ++it) {
                float v = arow[rr * 1024 + it * 64 + ln];
                unsigned long long m = __ballot(v != 0.f);
                if (ln == it) mym = m;
            }
            if (ln < 16) {
                uint2 st;
                st.x = (unsigned int)mym;
                st.y = (unsigned int)(mym >> 32);
                *(uint2*)(abits + ((size_t)blkr * 8 + wv * 2 + rr) * 32 + ln * 2) = st;
            }
        }
    } else {                                          // zero a_src+a_dst (contiguous 1 MB)
        int idx = (blk - 8704) * 256 + t;
        f32x4 z = {0.f, 0.f, 0.f, 0.f};
        *(f32x4*)(a_zero + (size_t)idx * 8) = z;
        *(f32x4*)(a_zero + (size_t)idx * 8 + 4) = z;
    }
}

// ---------- GEMM1: Xb @ BT^T -> h_bt (f16 [bh][o][n]) + gate (f16) + a_src/a_dst partials ----------
// BK=32, TRIPLE-buffered LDS, depth-2 pipeline with counted vmcnt (T4).
//   per step: s_waitcnt vmcnt(4)  (oldest stage, issued one full iter ago, resident)
//             s_barrier           (all waves' tile-t loads landed; compute(t-1) done)
//             stage(t+2)          (into the buffer tile t-1 just vacated)
//             compute(t)
// T2 swizzle for BK=32 geometry (conflict-free, verified 0 conflicts in rocprof).
__global__ __launch_bounds__(256) void gemm1_kernel(
        const unsigned short* __restrict__ Xb, const unsigned short* __restrict__ BT,
        const float* __restrict__ Hb, const float* __restrict__ w_src,
        const float* __restrict__ w_dst,
        unsigned short* __restrict__ h_bt, unsigned short* __restrict__ gate,
        float* __restrict__ a_src, float* __restrict__ a_dst) {
    __shared__ __align__(16) unsigned short As[3][128 * 32];   // 3 x 8KB
    __shared__ __align__(16) unsigned short Bs[3][128 * 32];   // 3 x 8KB
    __shared__ float hbs[128];
    __shared__ float ws_s[128], wd_s[128];
    int m0 = blockIdx.x * 128;
    int c0 = blockIdx.y * 128;
    int t = threadIdx.x;
    int w = t >> 6, lane = t & 63, l15 = t & 15, quad = lane >> 4;
    if (c0 >= 768) {
        if (t < 128) hbs[t] = Hb[c0 - 768 + t];
    } else {
        if (t < 128) {
            int c = c0 + t;
            int hd = c / OUT_DIM, o = c % OUT_DIM;
            ws_s[t] = w_src[hd * OUT_DIM + o];
            wd_s[t] = w_dst[hd * OUT_DIM + o];
        }
    }
    int uA0 = w * 2, uA1 = w * 2 + 1;
    int rA0 = uA0 * 16 + (lane >> 2), rA1 = uA1 * 16 + (lane >> 2);
    int qb = (lane & 3) ^ ((lane >> 3) & 3);       // inverse-swizzled 16B sub-block
    int qo = qb * 8;
    const unsigned short* gA0 = Xb + (size_t)(m0 + rA0) * IN_DIM + qo;
    const unsigned short* gA1 = Xb + (size_t)(m0 + rA1) * IN_DIM + qo;
    const unsigned short* gB0 = BT + (size_t)(c0 + rA0) * IN_DIM + qo;
    const unsigned short* gB1 = BT + (size_t)(c0 + rA1) * IN_DIM + qo;
    int swz = (quad ^ ((l15 >> 1) & 3)) * 8;
    int aoff0 = (w * 32 + l15) * 32 + swz;
    int aoff1 = aoff0 + 16 * 32;
    int boff  = l15 * 32 + swz;                    // + nt*512

    f32x4 acc[2][8] = {};

    auto stage = [&](unsigned short* Ad, unsigned short* Bd, int koff) {
        gload_lds16(gA0 + koff, Ad + uA0 * 512);
        gload_lds16(gA1 + koff, Ad + uA1 * 512);
        gload_lds16(gB0 + koff, Bd + uA0 * 512);
        gload_lds16(gB1 + koff, Bd + uA1 * 512);
    };
    auto compute = [&](const unsigned short* Ab, const unsigned short* Bb) {
        short8 af0 = *(const short8*)(Ab + aoff0);
        short8 af1 = *(const short8*)(Ab + aoff1);
        #pragma unroll
        for (int nt = 0; nt < 8; ++nt) {
            short8 bfr = *(const short8*)(Bb + boff + nt * 512);
            acc[0][nt] = mfma16(af0, bfr, acc[0][nt]);
            acc[1][nt] = mfma16(af1, bfr, acc[1][nt]);
        }
    };

    // prologue: two tiles in flight
    stage(&As[0][0], &Bs[0][0], 0);
    stage(&As[1][0], &Bs[1][0], 32);
    // main loop: tiles 0..20 in 3-step groups (buffer index compile-time)
    for (int ts = 0; ts < 21; ts += 3) {
        WAIT_VM4(); __builtin_amdgcn_s_barrier();
        stage(&As[2][0], &Bs[2][0], (ts + 2) * 32);
        compute(&As[0][0], &Bs[0][0]);
        WAIT_VM4(); __builtin_amdgcn_s_barrier();
        stage(&As[0][0], &Bs[0][0], (ts + 3) * 32);
        compute(&As[1][0], &Bs[1][0]);
        WAIT_VM4(); __builtin_amdgcn_s_barrier();
        stage(&As[1][0], &Bs[1][0], (ts + 4) * 32);
        compute(&As[2][0], &Bs[2][0]);
    }
    // tail: tiles 21(b0), 22(b1), 23(b2); 23 still needs staging
    WAIT_VM4(); __builtin_amdgcn_s_barrier();
    stage(&As[2][0], &Bs[2][0], 23 * 32);
    compute(&As[0][0], &Bs[0][0]);
    WAIT_VM4(); __builtin_amdgcn_s_barrier();
    compute(&As[1][0], &Bs[1][0]);
    WAIT_VM0(); __builtin_amdgcn_s_barrier();
    compute(&As[2][0], &Bs[2][0]);

    int b = m0 >> 10;
    if (c0 < 768) {
        int split = (c0 / 96 + 1) * 96 - c0;         // cols belonging to lower head
        int headlo = c0 / 96;
        #pragma unroll
        for (int mt = 0; mt < 2; ++mt) {
            int rowbase = m0 + w * 32 + mt * 16 + quad * 4;
            int nbase = rowbase & 1023;
            #pragma unroll
            for (int nt = 0; nt < 8; ++nt) {
                int c = c0 + nt * 16 + l15;
                int hh = c / OUT_DIM, o = c % OUT_DIM;
                union { unsigned int u2[2]; ushort4v u4; } pk;
                pk.u2[0] = pkrtz(acc[mt][nt][0], acc[mt][nt][1]);
                pk.u2[1] = pkrtz(acc[mt][nt][2], acc[mt][nt][3]);
                *(ushort4v*)(h_bt + ((size_t)(b * 8 + hh) * OUT_DIM + o) * NN + nbase) = pk.u4;
            }
            #pragma unroll
            for (int reg = 0; reg < 4; ++reg) {
                float psA = 0.f, pdA = 0.f, psB = 0.f, pdB = 0.f;
                #pragma unroll
                for (int nt = 0; nt < 8; ++nt) {
                    int cl = nt * 16 + l15;
                    float th = tanh_fast(acc[mt][nt][reg]);
                    float s = th * ws_s[cl], d = th * wd_s[cl];
                    if (cl < split) { psA += s; pdA += d; }
                    else            { psB += s; pdB += d; }
                }
                #pragma unroll
                for (int mk = 1; mk <= 8; mk <<= 1) {
                    psA += __shfl_xor(psA, mk); pdA += __shfl_xor(pdA, mk);
                    psB += __shfl_xor(psB, mk); pdB += __shfl_xor(pdB, mk);
                }
                if (l15 == 0) {
                    int n2 = nbase + reg;
                    int ilo = (b * 8 + headlo) * 1024 + n2;
                    atomicAdd(&a_src[ilo], psA * 1.44269504f);
                    atomicAdd(&a_dst[ilo], pdA * 1.44269504f);
                    atomicAdd(&a_src[ilo + 1024], psB * 1.44269504f);
                    atomicAdd(&a_dst[ilo + 1024], pdB * 1.44269504f);
                }
            }
        }
    } else {
        #pragma unroll
        for (int mt = 0; mt < 2; ++mt) {
            int rowbase = m0 + w * 32 + mt * 16 + quad * 4;
            #pragma unroll
            for (int nt = 0; nt < 8; ++nt) {
                int cl = nt * 16 + l15;
                int cg = c0 - 768 + cl;
                #pragma unroll
                for (int reg = 0; reg < 4; ++reg) {
                    float z = acc[mt][nt][reg] + hbs[cl];
                    float g = __builtin_amdgcn_rcpf(1.f + __builtin_amdgcn_exp2f(-1.44269504f * z));
                    gate[(size_t)(rowbase + reg) * 768 + cg] = f2h(g);
                }
            }
        }
    }
}

// ---------- attention + fused epilogue ----------
// 32 query-rows per wave (two accumulator groups) AND 2 blocks/CU: 256 threads,
// 4 waves, block covers 128 rows; grid = 64 bh x 8 i-tiles = 512 blocks.
__global__ __launch_bounds__(256) void attn_kernel(
        const unsigned short* __restrict__ h_bt, const unsigned int* __restrict__ abits,
        const float* __restrict__ a_src_g, const float* __restrict__ a_dst_g,
        const unsigned short* __restrict__ gate, const unsigned short* __restrict__ Xb,
        const float* __restrict__ bias, float* __restrict__ out) {
    __shared__ __align__(16) unsigned short hs[2][96 * 64];
    __shared__ __align__(16) float adst[1024];
    __shared__ float bias_s[96];
    int blk = blockIdx.x;
    int bh = (blk & 7) * 8 + ((blk >> 3) & 7);
    int i0 = (blk >> 6) * 128;                   // 8 i-tiles of 128 rows
    int b = bh >> 3, hh = bh & 7;
    int t = threadIdx.x;
    int w = t >> 6, lane = t & 63, l15 = t & 15, quad = lane >> 4;
    *(f32x4*)(adst + t * 4) = *(const f32x4*)(a_dst_g + bh * 1024 + t * 4);
    if (t < 96) bias_s[t] = bias[t];
    int irowA = i0 + w * 16 + l15;
    int irowB = irowA + 64;
    float siA = a_src_g[bh * 1024 + irowA];
    float siB = a_src_g[bh * 1024 + irowB];
    const unsigned short* hhp = h_bt + (size_t)bh * 96 * NN;
    // DMA tile 0 into hs[0] (4 waves, 3 chunks each)
    #pragma unroll
    for (int cc = 0; cc < 3; ++cc) {
        int u0 = (w * 3 + cc) * 64;
        int p = u0 + lane;
        int r = p >> 3, qs = p & 7, qqb = qs ^ (r & 7);
        gload_lds16(hhp + (size_t)r * NN + qqb * 8, (char*)&hs[0][0] + (size_t)u0 * 16);
    }
    const unsigned int* mrowA = abits + ((size_t)b * NN + irowA) * 32;
    const unsigned int* mrowB = abits + ((size_t)b * NN + irowB) * 32;
    uint2 mwA = *(const uint2*)(mrowA);
    uint2 mwB = *(const uint2*)(mrowB);
    f32x4 accA[7] = {}, accB[7] = {};
    short8 ones = {};
    if (l15 == 0) {
        #pragma unroll
        for (int u = 0; u < 8; ++u) ones[u] = (short)0x3C00;   // f16 1.0
    }
    auto build_af = [&](unsigned int byte, float si, const float* dvp) -> short8 {
        float ev[8];
        #pragma unroll
        for (int u = 0; u < 8; ++u) {
            float s = si + dvp[u];
            float l = fmaxf(s, 0.2f * s);
            float e = __builtin_amdgcn_exp2f(l);
            ev[u] = ((byte >> u) & 1u) ? e : 0.f;
        }
        union { unsigned int u4[4]; short8 s8; } pk;
        pk.u4[0] = pkrtz(ev[0], ev[1]);
        pk.u4[1] = pkrtz(ev[2], ev[3]);
        pk.u4[2] = pkrtz(ev[4], ev[5]);
        pk.u4[3] = pkrtz(ev[6], ev[7]);
        return pk.s8;
    };
    __syncthreads();
    for (int j0 = 0; j0 < 1024; j0 += 64) {
        int cur = (j0 >> 6) & 1;
        int jn = j0 + 64;
        // DMA next h tile into the other buffer (drained by the end-of-iter barrier)
        if (jn < 1024) {
            #pragma unroll
            for (int cc = 0; cc < 3; ++cc) {
                int u0 = (w * 3 + cc) * 64;
                int p = u0 + lane;
                int r = p >> 3, qs = p & 7, qqb = qs ^ (r & 7);
                gload_lds16(hhp + (size_t)r * NN + jn + qqb * 8, (char*)&hs[cur ^ 1][0] + (size_t)u0 * 16);
            }
        }
        // build both row-groups' A fragments; dv (a_dst slice) loaded once, shared
        short8 afA[2], afB[2];
        unsigned int mwsA[2] = {mwA.x, mwA.y};
        unsigned int mwsB[2] = {mwB.x, mwB.y};
        #pragma unroll
        for (int ks = 0; ks < 2; ++ks) {
            f32x4 d0 = *(const f32x4*)(&adst[j0 + ks * 32 + quad * 8]);
            f32x4 d1 = *(const f32x4*)(&adst[j0 + ks * 32 + quad * 8 + 4]);
            float dv[8] = {d0[0], d0[1], d0[2], d0[3], d1[0], d1[1], d1[2], d1[3]};
            unsigned int byA = (mwsA[ks] >> (quad * 8)) & 0xFFu;
            unsigned int byB = (mwsB[ks] >> (quad * 8)) & 0xFFu;
            afA[ks] = build_af(byA, siA, dv);
            afB[ks] = build_af(byB, siB, dv);
        }
        // prefetch masks for next iter
        if (jn < 1024) {
            mwA = *(const uint2*)(mrowA + (jn >> 5));
            mwB = *(const uint2*)(mrowB + (jn >> 5));
        }
        // MFMA on current buffer: each B fragment read once, used by both groups
        #pragma unroll
        for (int ks = 0; ks < 2; ++ks) {
            #pragma unroll
            for (int nt = 0; nt < 6; ++nt) {
                int r = nt * 16 + l15;
                int qs = (ks * 4 + quad) ^ (r & 7);
                short8 bfr = *(const short8*)(&hs[cur][(size_t)(r * 8 + qs) * 8]);
                accA[nt] = mfma16(afA[ks], bfr, accA[nt]);
                accB[nt] = mfma16(afB[ks], bfr, accB[nt]);
            }
            accA[6] = mfma16(afA[ks], ones, accA[6]);
            accB[6] = mfma16(afB[ks], ones, accB[6]);
        }
        __syncthreads();
    }
    // fused epilogue: bias + elu + precomputed f16 gate + f16 x + blend -> out
    auto epilog = [&](const f32x4 (&ac)[7], int rowoff) {
        int rowq = i0 + rowoff + w * 16 + quad * 4;
        #pragma unroll
        for (int reg = 0; reg < 4; ++reg) {
            float ssum = __shfl(ac[6][reg], (lane & 48));   // ones-column holds row sum
            float inv = (ssum > 0.f) ? __builtin_amdgcn_rcpf(ssum) : 0.f;
            int n = rowq + reg;
            size_t mrow_o = ((size_t)b * NN + n) * 768 + hh * 96;
            #pragma unroll
            for (int nt = 0; nt < 6; ++nt) {
                int cl = nt * 16 + l15;
                float v = ac[nt][reg] * inv + bias_s[cl];
                float e = (v > 0.f) ? v : (__builtin_amdgcn_exp2f(v * 1.44269504f) - 1.f);
                float g = h2f(gate[mrow_o + cl]);
                float x = h2f(Xb[mrow_o + cl]);
                out[mrow_o + cl] = x + g * (e - x);
            }
        }
    };
    epilog(accA, 0);
    epilog(accB, 64);
}

extern "C" void kernel_launch(void* const* d_in, const int* in_sizes, int n_in,
                              void* d_out, int out_size, void* d_ws, size_t ws_size,
                              hipStream_t stream) {
    const float* feat_in = (const float*)d_in[0];
    const float* adj     = (const float*)d_in[1];
    const float* W       = (const float*)d_in[2];
    const float* bbias   = (const float*)d_in[3];
    const float* w_src   = (const float*)d_in[4];
    const float* w_dst   = (const float*)d_in[5];
    const float* Hw      = (const float*)d_in[6];
    const float* Hb      = (const float*)d_in[7];
    float* out = (float*)d_out;
    char* base = (char*)d_ws;

    unsigned short* Xb    = (unsigned short*)(base);                 // 12,582,912 B (f16)
    unsigned short* BcatT = (unsigned short*)(base + 12582912);      //  2,359,296 B (f16)
    unsigned short* h_bt  = (unsigned short*)(base + 14942208);      // 12,582,912 B (f16)
    unsigned short* gate  = (unsigned short*)(base + 27525120);      // 12,582,912 B (f16)
    float* a_src = (float*)(base + 40108032);                        //    262,144 B
    float* a_dst = (float*)(base + 40370176);                        //    262,144 B (contiguous after a_src)
    unsigned int* abits = (unsigned int*)(base + 40632320);          //  1,048,576 B (end ~41.7 MB)

    prep_kernel<<<8768, 256, 0, stream>>>(feat_in, W, Hw, adj, Xb, BcatT, abits, a_src);
    gemm1_kernel<<<dim3(M_ROWS / 128, NCOLS / 128), 256, 0, stream>>>(
        Xb, BcatT, Hb, w_src, w_dst, h_bt, gate, a_src, a_dst);
    attn_kernel<<<512, 256, 0, stream>>>(h_bt, abits, a_src, a_dst, gate, Xb, bbias, out);
}